// Round 9
// baseline (228.196 us; speedup 1.0000x reference)
//
#include <hip/hip_runtime.h>

#define B_   4
#define T_   2048
#define D_   1024
#define MTOK 8192  // B_*T_

typedef __attribute__((ext_vector_type(8))) _Float16 half8;
typedef __attribute__((ext_vector_type(4))) float    f32x4;

#define GLD(G, L) __builtin_amdgcn_global_load_lds(                       \
    (const __attribute__((address_space(1))) void*)(G),                   \
    (__attribute__((address_space(3))) void*)(L), 16, 0, 0)

#define BAR()   __builtin_amdgcn_s_barrier()
#define LGKM0() do { asm volatile("s_waitcnt lgkmcnt(0)" ::: "memory");   \
                     __builtin_amdgcn_sched_barrier(0); } while (0)
#define VMW3()  asm volatile("s_waitcnt vmcnt(3)" ::: "memory")
#define VMW2()  asm volatile("s_waitcnt vmcnt(2)" ::: "memory")
#define VMW0()  asm volatile("s_waitcnt vmcnt(0)" ::: "memory")

__device__ __forceinline__ unsigned short f2h(float f) {
  return __builtin_bit_cast(unsigned short, (_Float16)f);  // RTE
}
__device__ __forceinline__ float h2f(unsigned short u) {
  return (float)__builtin_bit_cast(_Float16, u);
}

// ---------------- prep: x fp32 -> fp16 ------------------------------
__global__ __launch_bounds__(256) void tofp16_kernel(
    const float4* __restrict__ in, ushort4* __restrict__ out, int n4) {
  int i = blockIdx.x * 256 + threadIdx.x;
  if (i >= n4) return;
  float4 v = in[i];
  ushort4 h;
  h.x = f2h(v.x); h.y = f2h(v.y); h.z = f2h(v.z); h.w = f2h(v.w);
  out[i] = h;
}

// ---------------- prep: transpose + concat W -> fp16 ----------------
__global__ __launch_bounds__(256) void wcat_t_kernel(
    const float* __restrict__ Wq, const float* __restrict__ Wk,
    const float* __restrict__ Wv, unsigned short* __restrict__ Wt) {
  __shared__ float tile[32][33];
  int z = blockIdx.z;
  const float* W = (z == 0) ? Wq : ((z == 1) ? Wk : Wv);
  int c0 = blockIdx.x * 32, r0 = blockIdx.y * 32;
  int tx = threadIdx.x & 31, ty = threadIdx.x >> 5;  // 32 x 8
  #pragma unroll
  for (int i = 0; i < 4; ++i)
    tile[ty + i * 8][tx] = W[(size_t)(r0 + ty + i * 8) * D_ + c0 + tx];
  __syncthreads();
  #pragma unroll
  for (int i = 0; i < 4; ++i) {
    float v = tile[tx][ty + i * 8];
    size_t row = (size_t)z * D_ + c0 + ty + i * 8;
    Wt[row * D_ + r0 + tx] = f2h(v);
  }
}

// ---------------- V transpose: QKV cols [2048,3072) -> Vt[b][d][t] --
__global__ __launch_bounds__(256) void vtrans_kernel(
    const unsigned short* __restrict__ QKV, unsigned short* __restrict__ Vt) {
  __shared__ unsigned short tile[64][68];
  int b = blockIdx.z;
  int t0 = blockIdx.x * 64, d0 = blockIdx.y * 64;
  int l16 = threadIdx.x & 15, rr = threadIdx.x >> 4;
  const unsigned short* src =
      QKV + ((size_t)b * 2048 + t0 + rr) * 3072 + 2048 + d0 + l16 * 4;
  #pragma unroll
  for (int i = 0; i < 4; ++i) {
    ushort4 v = *(const ushort4*)(src + (size_t)i * 16 * 3072);
    *(ushort4*)&tile[rr + i * 16][l16 * 4] = v;
  }
  __syncthreads();
  unsigned short* dst = Vt + ((size_t)b * D_ + d0) * 2048 + t0;
  #pragma unroll
  for (int j = 0; j < 4; ++j) {
    int dd = rr + j * 16;
    int tt = l16 * 4;
    ushort4 v;
    v.x = tile[tt + 0][dd]; v.y = tile[tt + 1][dd];
    v.z = tile[tt + 2][dd]; v.w = tile[tt + 3][dd];
    *(ushort4*)(dst + (size_t)dd * 2048 + tt) = v;
  }
}

// ---------------- zero d_out + colsum -------------------------------
__global__ __launch_bounds__(256) void zero_kernel(float4* __restrict__ o,
                                                   int n4,
                                                   float4* __restrict__ cs,
                                                   int c4) {
  int i = blockIdx.x * 256 + threadIdx.x;
  float4 zz = {0.f, 0.f, 0.f, 0.f};
  if (i < n4) o[i] = zz;
  if (i < c4) cs[i] = zz;
}

// ---------------- 8-phase pipelined GEMM, BK=32, FM=4 ---------------
// C[m][n] = sum_k A[m][k]*B[n][k].  BM=128, BN=256, BK=32, 512 thr =
// 8 waves (2M x 4N).  LDS 48 KB (2 buf).
// EPI: 1 = fp16 row-major store; 2 = fp16 store + fused column-sum of
//      exp(s-64) via shfl reduce + atomicAdd into CS (scores pass).
template <int EPI>
__global__ __launch_bounds__(512, 4) void gemm8p(
    const unsigned short* __restrict__ A, const unsigned short* __restrict__ B,
    void* __restrict__ C0, float* __restrict__ CS,
    int K, int lda, int ldb, int ldc,
    long aBatch, long bBatch, long cBatch) {
  constexpr int ABY  = 128 * 64;        // 8192 B
  constexpr int BUFB = ABY + 16384;     // 24576 B
  __shared__ __align__(16) char lds[2 * BUFB];

  const int z = blockIdx.z;
  A += (size_t)z * aBatch;
  B += (size_t)z * bBatch;

  const int nwg = gridDim.x * gridDim.y;
  int s = blockIdx.y * gridDim.x + blockIdx.x;
  s = (s & 7) * (nwg >> 3) + (s >> 3);
  const int bx = s % gridDim.x, by = s / gridDim.x;
  const int brow = by * 128, bcol = bx * 256;

  const int tid = threadIdx.x;
  const int wid = tid >> 6, lane = tid & 63;
  const int wr = wid >> 2, wc = wid & 3;
  const int l15 = lane & 15, g4 = lane >> 4;

  const int scol = ((lane & 3) ^ ((lane >> 3) & 3)) * 8;
  const int srow = lane >> 2;
  int aoff, adst, boffs[2], bdst[2];
  {
    int r0 = wid * 16;  // whole A staged as one unit (phase 4 only)
    aoff = (brow + r0 + srow) * lda + scol;
    adst = r0 * 64;
    #pragma unroll
    for (int rg = 0; rg < 2; ++rg) {
      int rb = (wid >> 1) * 64 + rg * 32 + (wid & 1) * 16;  // B-nh{rg} union
      boffs[rg] = (bcol + rb + srow) * ldb + scol;
      bdst[rg]  = ABY + rb * 64;
    }
  }

  const int rslot = (g4 ^ ((l15 >> 1) & 3)) * 16;
  int aRd[2], bRd[2];
  #pragma unroll
  for (int mh = 0; mh < 2; ++mh) {
    aRd[mh] = (wr * 64 + mh * 32 + l15) * 64 + rslot;
    bRd[mh] = ABY + (wc * 64 + mh * 32 + l15) * 64 + rslot;
  }

#define STAGE_A(bb, tt) \
    GLD(A + (size_t)(aoff + (tt) * 32), lds + (bb) * BUFB + adst)
#define STAGE_B(nh, bb, tt) \
    GLD(B + (size_t)(boffs[nh] + (tt) * 32), lds + (bb) * BUFB + bdst[nh])
#define LOAD_A(mh) do { _Pragma("unroll")                                     \
    for (int mf = 0; mf < 2; ++mf)                                            \
      ar[mf] = *(const half8*)(buf + aRd[mh] + mf * 1024); } while (0)
#define LOAD_B(dst, nh) do { _Pragma("unroll")                                \
    for (int nf = 0; nf < 2; ++nf)                                            \
      dst[nf] = *(const half8*)(buf + bRd[nh] + nf * 1024); } while (0)
#define MFMA_Q(mh, nh, br) do { _Pragma("unroll")                             \
    for (int mf = 0; mf < 2; ++mf) { _Pragma("unroll")                        \
      for (int nf = 0; nf < 2; ++nf) {                                        \
        f32x4& ac = acc[(mh) * 2 + mf][(nh) * 2 + nf];                        \
        ac = __builtin_amdgcn_mfma_f32_16x16x32_f16(ar[mf], br[nf], ac, 0, 0, 0); \
      } } } while (0)

  // prologue: stage K-tiles 0 and 1
  STAGE_A(0, 0); STAGE_B(0, 0, 0); STAGE_B(1, 0, 0);
  STAGE_A(1, 1); STAGE_B(0, 1, 1); STAGE_B(1, 1, 1);
  VMW3();  // buf0 complete
  BAR();

  f32x4 acc[4][4] = {};
  half8 ar[2], b0r[2], b1r[2];
  const int nIter = K / 64;

  for (int it = 0; it < nIter; ++it) {
    const bool st = (it + 1 < nIter);
    #pragma unroll
    for (int h = 0; h < 2; ++h) {
      const char* buf = lds + h * BUFB;
      const int tt = 2 * it + 2 + h;
      // phase 1: read A-mh0 + B-nh0
      LOAD_A(0); LOAD_B(b0r, 0);
      BAR(); LGKM0();
      __builtin_amdgcn_s_setprio(1); MFMA_Q(0, 0, b0r);
      __builtin_amdgcn_s_setprio(0); BAR();
      // phase 2: read B-nh1; restage B-nh0
      LOAD_B(b1r, 1);
      if (st) STAGE_B(0, h, tt);
      BAR(); LGKM0();
      __builtin_amdgcn_s_setprio(1); MFMA_Q(0, 1, b1r);
      __builtin_amdgcn_s_setprio(0); BAR();
      // phase 3: read A-mh1; restage B-nh1
      LOAD_A(1);
      if (st) STAGE_B(1, h, tt);
      BAR(); LGKM0();
      __builtin_amdgcn_s_setprio(1); MFMA_Q(1, 1, b1r);
      __builtin_amdgcn_s_setprio(0); BAR();
      // phase 4: restage whole A (freed after phase 3)
      if (st) STAGE_A(h, tt);
      BAR();
      __builtin_amdgcn_s_setprio(1); MFMA_Q(1, 0, b0r);
      __builtin_amdgcn_s_setprio(0);
      if (st) { VMW3(); } else { VMW0(); }
      BAR();
    }
  }

  // epilogue
  if constexpr (EPI == 1) {
    unsigned short* C = (unsigned short*)C0 + (size_t)z * cBatch;
    #pragma unroll
    for (int m = 0; m < 4; ++m) {
      int rowoff = (m >> 1) * 32 + (m & 1) * 16;
      #pragma unroll
      for (int n = 0; n < 4; ++n) {
        int coloff = (n >> 1) * 32 + (n & 1) * 16;
        #pragma unroll
        for (int r = 0; r < 4; ++r) {
          int row = brow + wr * 64 + rowoff + g4 * 4 + r;
          int col = bcol + wc * 64 + coloff + l15;
          C[(size_t)row * ldc + col] = f2h(acc[m][n][r]);
        }
      }
    }
  } else {  // EPI == 2: fp16 store + fused colsum of exp(s-64)
    unsigned short* C = (unsigned short*)C0 + (size_t)z * cBatch;
    float csum[4] = {0.f, 0.f, 0.f, 0.f};
    #pragma unroll
    for (int m = 0; m < 4; ++m) {
      int rowoff = (m >> 1) * 32 + (m & 1) * 16;
      #pragma unroll
      for (int n = 0; n < 4; ++n) {
        int coloff = (n >> 1) * 32 + (n & 1) * 16;
        #pragma unroll
        for (int r = 0; r < 4; ++r) {
          int row = brow + wr * 64 + rowoff + g4 * 4 + r;
          int col = bcol + wc * 64 + coloff + l15;
          unsigned short hh = f2h(acc[m][n][r]);
          C[(size_t)row * ldc + col] = hh;
          csum[n] += __expf(h2f(hh) - 64.0f);  // exact match with PV weights
        }
      }
    }
    #pragma unroll
    for (int n = 0; n < 4; ++n) {
      csum[n] += __shfl_xor(csum[n], 16);
      csum[n] += __shfl_xor(csum[n], 32);
    }
    if (g4 == 0) {
      #pragma unroll
      for (int n = 0; n < 4; ++n) {
        int col = bcol + wc * 64 + (n >> 1) * 32 + (n & 1) * 16 + l15;
        unsafeAtomicAdd(CS + (size_t)z * T_ + col, csum[n]);
      }
    }
  }
#undef STAGE_A
#undef STAGE_B
#undef LOAD_A
#undef LOAD_B
#undef MFMA_Q
}

// ---------------- PV GEMM, K-split x2, fused exp*u A-staging --------
// out[q][d] += sum_{k in half kh} w[q][k] * Vt[d][k],
// w = exp(s-64)*u[k] computed in reg-staging.  grid (4,16,8): z = b*2+kh,
// each block K=1024 (32 tiles) -> 512 blocks = 2 blocks/CU.
// Epilogue: unsafeAtomicAdd into pre-zeroed out (2 commutative adds/elem
// -> deterministic).
__global__ __launch_bounds__(512, 2) void gemmPV(
    const unsigned short* __restrict__ Sc, const float* __restrict__ U,
    const unsigned short* __restrict__ Bv, float* __restrict__ out) {
  constexpr int ABY  = 128 * 64;
  constexpr int BUFB = ABY + 16384;
  __shared__ __align__(16) char lds[2 * BUFB];

  const int z  = blockIdx.z;
  const int b  = z >> 1, kh = z & 1;
  const int k0 = kh * 1024;
  Sc += (size_t)b * T_ * T_;
  U  += (size_t)b * T_ + k0;
  Bv += (size_t)b * D_ * T_;
  float* Co = out + (size_t)b * T_ * D_;

  const int nwg = gridDim.x * gridDim.y;
  int s = blockIdx.y * gridDim.x + blockIdx.x;
  s = (s & 7) * (nwg >> 3) + (s >> 3);
  const int bx = s % gridDim.x, by = s / gridDim.x;
  const int brow = by * 128, bcol = bx * 256;

  const int tid = threadIdx.x;
  const int wid = tid >> 6, lane = tid & 63;
  const int wr = wid >> 2, wc = wid & 3;
  const int l15 = lane & 15, g4 = lane >> 4;

  // A reg-staging geometry (linear source, swizzled LDS write)
  const int arow = wid * 16 + (lane >> 2);
  const unsigned short* aSrc =
      Sc + (size_t)(brow + arow) * T_ + k0 + (lane & 3) * 8;
  const int awB  = arow * 64 + ((lane & 3) ^ ((lane >> 3) & 3)) * 16;
  const int ucol = (lane & 3) * 8;

  // B GLD geometry (inverse-swizzled source)
  const int scol = ((lane & 3) ^ ((lane >> 3) & 3)) * 8;
  const int srow = lane >> 2;
  int boffs[2], bdst[2];
  #pragma unroll
  for (int rg = 0; rg < 2; ++rg) {
    int rb = (wid >> 1) * 64 + rg * 32 + (wid & 1) * 16;
    boffs[rg] = (bcol + rb + srow) * T_ + k0 + scol;
    bdst[rg]  = ABY + rb * 64;
  }

  const int rslot = (g4 ^ ((l15 >> 1) & 3)) * 16;
  int aRd[2], bRd[2];
  #pragma unroll
  for (int mh = 0; mh < 2; ++mh) {
    aRd[mh] = (wr * 64 + mh * 32 + l15) * 64 + rslot;
    bRd[mh] = ABY + (wc * 64 + mh * 32 + l15) * 64 + rslot;
  }

  uint4 rawA;
  float4 uva, uvb;

#define PV_STAGE_B(nh, bb, tt) \
    GLD(Bv + (size_t)(boffs[nh] + (tt) * 32), lds + (bb) * BUFB + bdst[nh])
#define PV_AISSUE(tt) do {                                                    \
    rawA = *(const uint4*)(aSrc + (size_t)(tt) * 32);                         \
    uva  = *(const float4*)(U + (tt) * 32 + ucol);                            \
    uvb  = *(const float4*)(U + (tt) * 32 + ucol + 4); } while (0)
#define PV_AWRITE(bb) do {                                                    \
    const unsigned short* hp = (const unsigned short*)&rawA;                  \
    float uu[8] = {uva.x, uva.y, uva.z, uva.w, uvb.x, uvb.y, uvb.z, uvb.w};   \
    unsigned int w_[4];                                                       \
    _Pragma("unroll") for (int j = 0; j < 4; ++j) {                           \
      float w0 = __expf(h2f(hp[2 * j])     - 64.f) * uu[2 * j];               \
      float w1 = __expf(h2f(hp[2 * j + 1]) - 64.f) * uu[2 * j + 1];           \
      w_[j] = (unsigned int)f2h(w0) | ((unsigned int)f2h(w1) << 16); }        \
    *(uint4*)(lds + (bb) * BUFB + awB) = *(uint4*)w_; } while (0)
#define PV_LOAD_A(mh) do { _Pragma("unroll")                                  \
    for (int mf = 0; mf < 2; ++mf)                                            \
      ar[mf] = *(const half8*)(buf + aRd[mh] + mf * 1024); } while (0)
#define PV_LOAD_B(dst, nh) do { _Pragma("unroll")                             \
    for (int nf = 0; nf < 2; ++nf)                                            \
      dst[nf] = *(const half8*)(buf + bRd[nh] + nf * 1024); } while (0)
#define PV_MFMA(mh, nh, br) do { _Pragma("unroll")                            \
    for (int mf = 0; mf < 2; ++mf) { _Pragma("unroll")                        \
      for (int nf = 0; nf < 2; ++nf) {                                        \
        f32x4& ac = acc[(mh) * 2 + mf][(nh) * 2 + nf];                        \
        ac = __builtin_amdgcn_mfma_f32_16x16x32_f16(ar[mf], br[nf], ac, 0, 0, 0); \
      } } } while (0)

  // prologue: tiles 0 (buf0) and 1 (buf1)
  PV_AISSUE(0);
  PV_STAGE_B(0, 0, 0); PV_STAGE_B(1, 0, 0);
  uint4 rawA1 = *(const uint4*)(aSrc + 32);
  float4 uva1 = *(const float4*)(U + 32 + ucol);
  float4 uvb1 = *(const float4*)(U + 32 + ucol + 4);
  PV_STAGE_B(0, 1, 1); PV_STAGE_B(1, 1, 1);
  VMW2();  // A/u data ready
  PV_AWRITE(0);
  rawA = rawA1; uva = uva1; uvb = uvb1;
  PV_AWRITE(1);
  asm volatile("s_waitcnt lgkmcnt(0)" ::: "memory");
  BAR();
  VMW0();  // buf0+buf1 B complete before first reads

  f32x4 acc[4][4] = {};
  half8 ar[2], b0r[2], b1r[2];
  const int NT = 1024 / 32;  // 32 K-tiles per block

  for (int it = 0; it < NT / 2; ++it) {
    #pragma unroll
    for (int h = 0; h < 2; ++h) {
      const char* buf = lds + h * BUFB;
      const int tt = 2 * it + 2 + h;
      const bool st = (tt < NT);
      // phase 1
      PV_LOAD_A(0); PV_LOAD_B(b0r, 0);
      if (st) PV_AISSUE(tt);
      BAR(); LGKM0();
      __builtin_amdgcn_s_setprio(1); PV_MFMA(0, 0, b0r);
      __builtin_amdgcn_s_setprio(0); BAR();
      // phase 2
      PV_LOAD_B(b1r, 1);
      if (st) PV_STAGE_B(0, h, tt);
      BAR(); LGKM0();
      __builtin_amdgcn_s_setprio(1); PV_MFMA(0, 1, b1r);
      __builtin_amdgcn_s_setprio(0); BAR();
      // phase 3
      PV_LOAD_A(1);
      if (st) PV_STAGE_B(1, h, tt);
      BAR(); LGKM0();
      __builtin_amdgcn_s_setprio(1); PV_MFMA(1, 1, b1r);
      __builtin_amdgcn_s_setprio(0); BAR();
      // phase 4: drain A/u + prior B, write exp*u tile, drain ds_write
      if (st) {
        VMW2(); PV_AWRITE(h);
        asm volatile("s_waitcnt lgkmcnt(0)" ::: "memory");
      }
      BAR();
      __builtin_amdgcn_s_setprio(1); PV_MFMA(1, 0, b0r);
      __builtin_amdgcn_s_setprio(0);
      if (!st) VMW0();
      BAR();
    }
  }

  #pragma unroll
  for (int m = 0; m < 4; ++m) {
    int rowoff = (m >> 1) * 32 + (m & 1) * 16;
    #pragma unroll
    for (int n = 0; n < 4; ++n) {
      int coloff = (n >> 1) * 32 + (n & 1) * 16;
      #pragma unroll
      for (int r = 0; r < 4; ++r) {
        int row = brow + wr * 64 + rowoff + g4 * 4 + r;
        int col = bcol + wc * 64 + coloff + l15;
        unsafeAtomicAdd(&Co[(size_t)row * D_ + col], acc[m][n][r]);
      }
    }
  }
#undef PV_STAGE_B
#undef PV_AISSUE
#undef PV_AWRITE
#undef PV_LOAD_A
#undef PV_LOAD_B
#undef PV_MFMA
}

// ------- invert column sums ----------------------------------------
__global__ __launch_bounds__(256) void sm_stats(const float* __restrict__ cs,
                                                float* __restrict__ stats) {
  int i = blockIdx.x * 256 + threadIdx.x;  // b*2048 + k
  stats[i] = 1.0f / cs[i];
}

// --------------------------------------------------------------------
extern "C" void kernel_launch(void* const* d_in, const int* in_sizes, int n_in,
                              void* d_out, int out_size, void* d_ws, size_t ws_size,
                              hipStream_t stream) {
  const float* x  = (const float*)d_in[0];
  const float* Wq = (const float*)d_in[1];
  const float* Wk = (const float*)d_in[2];
  const float* Wv = (const float*)d_in[3];
  float* out = (float*)d_out;

  char* ws = (char*)d_ws;
  const size_t MB = 1024ull * 1024ull;
  unsigned short* scoresh = (unsigned short*)(ws);             // 32 MB fp16
  unsigned short* QKVh = (unsigned short*)(ws + 32 * MB);      // 48 MB [8192][3072]
  unsigned short* Vt   = (unsigned short*)(ws + 80 * MB);      // 16 MB [4][1024][2048]
  unsigned short* xh   = (unsigned short*)(ws + 96 * MB);      // 16 MB fp16 x
  unsigned short* Wt   = (unsigned short*)(ws + 112 * MB);     // 6 MB  [3072][1024]
  float* colsum = (float*)(ws + 118 * MB);                     // 32 KB [4][2048]
  float* stats  = (float*)(ws + 118 * MB + 64 * 1024);         // 32 KB fp32 u

  // 1. x -> fp16
  tofp16_kernel<<<MTOK * D_ / 4 / 256, 256, 0, stream>>>(
      (const float4*)x, (ushort4*)xh, MTOK * D_ / 4);

  // 2. transpose + concat W -> fp16
  wcat_t_kernel<<<dim3(32, 32, 3), 256, 0, stream>>>(Wq, Wk, Wv, Wt);

  // 3. fused QKV projection (FM=4, 768 blocks -> 3 blocks/CU)
  gemm8p<1><<<dim3(3072 / 256, MTOK / 128, 1), 512, 0, stream>>>(
      xh, Wt, QKVh, nullptr, D_, D_, D_, 3072, 0, 0, 0);

  // 4. V transpose -> Vt[b][d][t]
  vtrans_kernel<<<dim3(T_ / 64, D_ / 64, B_), 256, 0, stream>>>(QKVh, Vt);

  // 5. zero d_out (32 MB) + colsum (32 KB) for the atomic passes
  zero_kernel<<<MTOK * D_ / 4 / 256, 256, 0, stream>>>(
      (float4*)out, MTOK * D_ / 4, (float4*)colsum, B_ * T_ / 4);

  // 6. scores = Q K^T, fp16 out + fused column-sum of exp(s-64)
  gemm8p<2><<<dim3(T_ / 256, T_ / 128, B_), 512, 0, stream>>>(
      QKVh, QKVh + 1024, scoresh, colsum, D_, 3072, 3072, T_,
      (long)T_ * 3072, (long)T_ * 3072, (long)T_ * T_);

  // 7. u = 1/colsum
  sm_stats<<<B_ * T_ / 256, 256, 0, stream>>>(colsum, stats);

  // 8. out += exp(S-64)*u @ V, K-split x2 (512 blocks = 2/CU), atomics
  gemmPV<<<dim3(D_ / 256, T_ / 128, 2 * B_), 512, 0, stream>>>(
      scoresh, stats, Vt, out);
}

// Round 10
// 200.215 us; speedup vs baseline: 1.1398x; 1.1398x over previous
//
#include <hip/hip_runtime.h>

#define B_   4
#define T_   2048
#define D_   1024
#define MTOK 8192  // B_*T_

typedef __attribute__((ext_vector_type(8))) _Float16 half8;
typedef __attribute__((ext_vector_type(4))) float    f32x4;

#define GLD(G, L) __builtin_amdgcn_global_load_lds(                       \
    (const __attribute__((address_space(1))) void*)(G),                   \
    (__attribute__((address_space(3))) void*)(L), 16, 0, 0)

#define BAR()   __builtin_amdgcn_s_barrier()
#define LGKM0() do { asm volatile("s_waitcnt lgkmcnt(0)" ::: "memory");   \
                     __builtin_amdgcn_sched_barrier(0); } while (0)
#define VMW3()  asm volatile("s_waitcnt vmcnt(3)" ::: "memory")
#define VMW2()  asm volatile("s_waitcnt vmcnt(2)" ::: "memory")
#define VMW0()  asm volatile("s_waitcnt vmcnt(0)" ::: "memory")

__device__ __forceinline__ unsigned short f2h(float f) {
  return __builtin_bit_cast(unsigned short, (_Float16)f);  // RTE
}
__device__ __forceinline__ float h2f(unsigned short u) {
  return (float)__builtin_bit_cast(_Float16, u);
}

// ---------------- prep: x fp32 -> fp16 (+ zero colsum) --------------
__global__ __launch_bounds__(256) void tofp16_kernel(
    const float4* __restrict__ in, ushort4* __restrict__ out, int n4,
    float4* __restrict__ cs, int c4) {
  int i = blockIdx.x * 256 + threadIdx.x;
  if (i < c4) cs[i] = (float4){0.f, 0.f, 0.f, 0.f};
  if (i >= n4) return;
  float4 v = in[i];
  ushort4 h;
  h.x = f2h(v.x); h.y = f2h(v.y); h.z = f2h(v.z); h.w = f2h(v.w);
  out[i] = h;
}

// ---------------- prep: transpose + concat W -> fp16 ----------------
__global__ __launch_bounds__(256) void wcat_t_kernel(
    const float* __restrict__ Wq, const float* __restrict__ Wk,
    const float* __restrict__ Wv, unsigned short* __restrict__ Wt) {
  __shared__ float tile[32][33];
  int z = blockIdx.z;
  const float* W = (z == 0) ? Wq : ((z == 1) ? Wk : Wv);
  int c0 = blockIdx.x * 32, r0 = blockIdx.y * 32;
  int tx = threadIdx.x & 31, ty = threadIdx.x >> 5;  // 32 x 8
  #pragma unroll
  for (int i = 0; i < 4; ++i)
    tile[ty + i * 8][tx] = W[(size_t)(r0 + ty + i * 8) * D_ + c0 + tx];
  __syncthreads();
  #pragma unroll
  for (int i = 0; i < 4; ++i) {
    float v = tile[tx][ty + i * 8];
    size_t row = (size_t)z * D_ + c0 + ty + i * 8;
    Wt[row * D_ + r0 + tx] = f2h(v);
  }
}

// ---------------- V transpose: QKV cols [2048,3072) -> Vt[b][d][t] --
__global__ __launch_bounds__(256) void vtrans_kernel(
    const unsigned short* __restrict__ QKV, unsigned short* __restrict__ Vt) {
  __shared__ unsigned short tile[64][68];
  int b = blockIdx.z;
  int t0 = blockIdx.x * 64, d0 = blockIdx.y * 64;
  int l16 = threadIdx.x & 15, rr = threadIdx.x >> 4;
  const unsigned short* src =
      QKV + ((size_t)b * 2048 + t0 + rr) * 3072 + 2048 + d0 + l16 * 4;
  #pragma unroll
  for (int i = 0; i < 4; ++i) {
    ushort4 v = *(const ushort4*)(src + (size_t)i * 16 * 3072);
    *(ushort4*)&tile[rr + i * 16][l16 * 4] = v;
  }
  __syncthreads();
  unsigned short* dst = Vt + ((size_t)b * D_ + d0) * 2048 + t0;
  #pragma unroll
  for (int j = 0; j < 4; ++j) {
    int dd = rr + j * 16;
    int tt = l16 * 4;
    ushort4 v;
    v.x = tile[tt + 0][dd]; v.y = tile[tt + 1][dd];
    v.z = tile[tt + 2][dd]; v.w = tile[tt + 3][dd];
    *(ushort4*)(dst + (size_t)dd * 2048 + tt) = v;
  }
}

// ---------------- 8-phase pipelined GEMM, BK=32, FM=4 ---------------
// C[m][n] = sum_k A[m][k]*B[n][k].  BM=128, BN=256, BK=32, 512 thr =
// 8 waves (2M x 4N).  LDS 48 KB (2 buf).
// EPI: 1 = fp16 row-major store; 2 = fp16 store + fused column-sum of
//      exp(s-64) via shfl reduce + atomicAdd into CS (scores pass).
template <int EPI>
__global__ __launch_bounds__(512, 4) void gemm8p(
    const unsigned short* __restrict__ A, const unsigned short* __restrict__ B,
    void* __restrict__ C0, float* __restrict__ CS,
    int K, int lda, int ldb, int ldc,
    long aBatch, long bBatch, long cBatch) {
  constexpr int ABY  = 128 * 64;        // 8192 B
  constexpr int BUFB = ABY + 16384;     // 24576 B
  __shared__ __align__(16) char lds[2 * BUFB];

  const int z = blockIdx.z;
  A += (size_t)z * aBatch;
  B += (size_t)z * bBatch;

  const int nwg = gridDim.x * gridDim.y;
  int s = blockIdx.y * gridDim.x + blockIdx.x;
  s = (s & 7) * (nwg >> 3) + (s >> 3);
  const int bx = s % gridDim.x, by = s / gridDim.x;
  const int brow = by * 128, bcol = bx * 256;

  const int tid = threadIdx.x;
  const int wid = tid >> 6, lane = tid & 63;
  const int wr = wid >> 2, wc = wid & 3;
  const int l15 = lane & 15, g4 = lane >> 4;

  const int scol = ((lane & 3) ^ ((lane >> 3) & 3)) * 8;
  const int srow = lane >> 2;
  int aoff, adst, boffs[2], bdst[2];
  {
    int r0 = wid * 16;  // whole A staged as one unit (phase 4 only)
    aoff = (brow + r0 + srow) * lda + scol;
    adst = r0 * 64;
    #pragma unroll
    for (int rg = 0; rg < 2; ++rg) {
      int rb = (wid >> 1) * 64 + rg * 32 + (wid & 1) * 16;  // B-nh{rg} union
      boffs[rg] = (bcol + rb + srow) * ldb + scol;
      bdst[rg]  = ABY + rb * 64;
    }
  }

  const int rslot = (g4 ^ ((l15 >> 1) & 3)) * 16;
  int aRd[2], bRd[2];
  #pragma unroll
  for (int mh = 0; mh < 2; ++mh) {
    aRd[mh] = (wr * 64 + mh * 32 + l15) * 64 + rslot;
    bRd[mh] = ABY + (wc * 64 + mh * 32 + l15) * 64 + rslot;
  }

#define STAGE_A(bb, tt) \
    GLD(A + (size_t)(aoff + (tt) * 32), lds + (bb) * BUFB + adst)
#define STAGE_B(nh, bb, tt) \
    GLD(B + (size_t)(boffs[nh] + (tt) * 32), lds + (bb) * BUFB + bdst[nh])
#define LOAD_A(mh) do { _Pragma("unroll")                                     \
    for (int mf = 0; mf < 2; ++mf)                                            \
      ar[mf] = *(const half8*)(buf + aRd[mh] + mf * 1024); } while (0)
#define LOAD_B(dst, nh) do { _Pragma("unroll")                                \
    for (int nf = 0; nf < 2; ++nf)                                            \
      dst[nf] = *(const half8*)(buf + bRd[nh] + nf * 1024); } while (0)
#define MFMA_Q(mh, nh, br) do { _Pragma("unroll")                             \
    for (int mf = 0; mf < 2; ++mf) { _Pragma("unroll")                        \
      for (int nf = 0; nf < 2; ++nf) {                                        \
        f32x4& ac = acc[(mh) * 2 + mf][(nh) * 2 + nf];                        \
        ac = __builtin_amdgcn_mfma_f32_16x16x32_f16(ar[mf], br[nf], ac, 0, 0, 0); \
      } } } while (0)

  // prologue: stage K-tiles 0 and 1
  STAGE_A(0, 0); STAGE_B(0, 0, 0); STAGE_B(1, 0, 0);
  STAGE_A(1, 1); STAGE_B(0, 1, 1); STAGE_B(1, 1, 1);
  VMW3();  // buf0 complete
  BAR();

  f32x4 acc[4][4] = {};
  half8 ar[2], b0r[2], b1r[2];
  const int nIter = K / 64;

  for (int it = 0; it < nIter; ++it) {
    const bool st = (it + 1 < nIter);
    #pragma unroll
    for (int h = 0; h < 2; ++h) {
      const char* buf = lds + h * BUFB;
      const int tt = 2 * it + 2 + h;
      // phase 1: read A-mh0 + B-nh0
      LOAD_A(0); LOAD_B(b0r, 0);
      BAR(); LGKM0();
      __builtin_amdgcn_s_setprio(1); MFMA_Q(0, 0, b0r);
      __builtin_amdgcn_s_setprio(0); BAR();
      // phase 2: read B-nh1; restage B-nh0
      LOAD_B(b1r, 1);
      if (st) STAGE_B(0, h, tt);
      BAR(); LGKM0();
      __builtin_amdgcn_s_setprio(1); MFMA_Q(0, 1, b1r);
      __builtin_amdgcn_s_setprio(0); BAR();
      // phase 3: read A-mh1; restage B-nh1
      LOAD_A(1);
      if (st) STAGE_B(1, h, tt);
      BAR(); LGKM0();
      __builtin_amdgcn_s_setprio(1); MFMA_Q(1, 1, b1r);
      __builtin_amdgcn_s_setprio(0); BAR();
      // phase 4: restage whole A (freed after phase 3)
      if (st) STAGE_A(h, tt);
      BAR();
      __builtin_amdgcn_s_setprio(1); MFMA_Q(1, 0, b0r);
      __builtin_amdgcn_s_setprio(0);
      if (st) { VMW3(); } else { VMW0(); }
      BAR();
    }
  }

  // epilogue
  if constexpr (EPI == 1) {
    unsigned short* C = (unsigned short*)C0 + (size_t)z * cBatch;
    #pragma unroll
    for (int m = 0; m < 4; ++m) {
      int rowoff = (m >> 1) * 32 + (m & 1) * 16;
      #pragma unroll
      for (int n = 0; n < 4; ++n) {
        int coloff = (n >> 1) * 32 + (n & 1) * 16;
        #pragma unroll
        for (int r = 0; r < 4; ++r) {
          int row = brow + wr * 64 + rowoff + g4 * 4 + r;
          int col = bcol + wc * 64 + coloff + l15;
          C[(size_t)row * ldc + col] = f2h(acc[m][n][r]);
        }
      }
    }
  } else {  // EPI == 2: fp16 store + fused colsum of exp(s-64)
    unsigned short* C = (unsigned short*)C0 + (size_t)z * cBatch;
    float csum[4] = {0.f, 0.f, 0.f, 0.f};
    #pragma unroll
    for (int m = 0; m < 4; ++m) {
      int rowoff = (m >> 1) * 32 + (m & 1) * 16;
      #pragma unroll
      for (int n = 0; n < 4; ++n) {
        int coloff = (n >> 1) * 32 + (n & 1) * 16;
        #pragma unroll
        for (int r = 0; r < 4; ++r) {
          int row = brow + wr * 64 + rowoff + g4 * 4 + r;
          int col = bcol + wc * 64 + coloff + l15;
          unsigned short hh = f2h(acc[m][n][r]);
          C[(size_t)row * ldc + col] = hh;
          csum[n] += __expf(h2f(hh) - 64.0f);  // exact match with PV weights
        }
      }
    }
    #pragma unroll
    for (int n = 0; n < 4; ++n) {
      csum[n] += __shfl_xor(csum[n], 16);
      csum[n] += __shfl_xor(csum[n], 32);
    }
    if (g4 == 0) {
      #pragma unroll
      for (int n = 0; n < 4; ++n) {
        int col = bcol + wc * 64 + (n >> 1) * 32 + (n & 1) * 16 + l15;
        unsafeAtomicAdd(CS + (size_t)z * T_ + col, csum[n]);
      }
    }
  }
#undef STAGE_A
#undef STAGE_B
#undef LOAD_A
#undef LOAD_B
#undef MFMA_Q
}

// ---------------- PV GEMM with fused exp*u A-staging ----------------
// out[q][d] = sum_k w[q][k] * Vt[d][k],  w = exp(s-64)*u[k] computed in
// reg-staging (global fp16 s -> exp*u -> swizzled ds_write_b128).
// grid (4,16,4) = 256 blocks; plain coalesced fp32 stores.
__global__ __launch_bounds__(512, 2) void gemmPV(
    const unsigned short* __restrict__ Sc, const float* __restrict__ U,
    const unsigned short* __restrict__ Bv, float* __restrict__ out) {
  constexpr int ABY  = 128 * 64;
  constexpr int BUFB = ABY + 16384;
  __shared__ __align__(16) char lds[2 * BUFB];

  const int b = blockIdx.z;
  Sc += (size_t)b * T_ * T_;
  U  += (size_t)b * T_;
  Bv += (size_t)b * D_ * T_;
  float* Co = out + (size_t)b * T_ * D_;

  const int nwg = gridDim.x * gridDim.y;
  int s = blockIdx.y * gridDim.x + blockIdx.x;
  s = (s & 7) * (nwg >> 3) + (s >> 3);
  const int bx = s % gridDim.x, by = s / gridDim.x;
  const int brow = by * 128, bcol = bx * 256;

  const int tid = threadIdx.x;
  const int wid = tid >> 6, lane = tid & 63;
  const int wr = wid >> 2, wc = wid & 3;
  const int l15 = lane & 15, g4 = lane >> 4;

  // A reg-staging geometry (linear source, swizzled LDS write)
  const int arow = wid * 16 + (lane >> 2);
  const unsigned short* aSrc = Sc + (size_t)(brow + arow) * T_ + (lane & 3) * 8;
  const int awB  = arow * 64 + ((lane & 3) ^ ((lane >> 3) & 3)) * 16;
  const int ucol = (lane & 3) * 8;

  // B GLD geometry (inverse-swizzled source)
  const int scol = ((lane & 3) ^ ((lane >> 3) & 3)) * 8;
  const int srow = lane >> 2;
  int boffs[2], bdst[2];
  #pragma unroll
  for (int rg = 0; rg < 2; ++rg) {
    int rb = (wid >> 1) * 64 + rg * 32 + (wid & 1) * 16;
    boffs[rg] = (bcol + rb + srow) * T_ + scol;
    bdst[rg]  = ABY + rb * 64;
  }

  const int rslot = (g4 ^ ((l15 >> 1) & 3)) * 16;
  int aRd[2], bRd[2];
  #pragma unroll
  for (int mh = 0; mh < 2; ++mh) {
    aRd[mh] = (wr * 64 + mh * 32 + l15) * 64 + rslot;
    bRd[mh] = ABY + (wc * 64 + mh * 32 + l15) * 64 + rslot;
  }

  uint4 rawA;
  float4 uva, uvb;

#define PV_STAGE_B(nh, bb, tt) \
    GLD(Bv + (size_t)(boffs[nh] + (tt) * 32), lds + (bb) * BUFB + bdst[nh])
#define PV_AISSUE(tt) do {                                                    \
    rawA = *(const uint4*)(aSrc + (size_t)(tt) * 32);                         \
    uva  = *(const float4*)(U + (tt) * 32 + ucol);                            \
    uvb  = *(const float4*)(U + (tt) * 32 + ucol + 4); } while (0)
#define PV_AWRITE(bb) do {                                                    \
    const unsigned short* hp = (const unsigned short*)&rawA;                  \
    float uu[8] = {uva.x, uva.y, uva.z, uva.w, uvb.x, uvb.y, uvb.z, uvb.w};   \
    unsigned int w_[4];                                                       \
    _Pragma("unroll") for (int j = 0; j < 4; ++j) {                           \
      float w0 = __expf(h2f(hp[2 * j])     - 64.f) * uu[2 * j];               \
      float w1 = __expf(h2f(hp[2 * j + 1]) - 64.f) * uu[2 * j + 1];           \
      w_[j] = (unsigned int)f2h(w0) | ((unsigned int)f2h(w1) << 16); }        \
    *(uint4*)(lds + (bb) * BUFB + awB) = *(uint4*)w_; } while (0)
#define PV_LOAD_A(mh) do { _Pragma("unroll")                                  \
    for (int mf = 0; mf < 2; ++mf)                                            \
      ar[mf] = *(const half8*)(buf + aRd[mh] + mf * 1024); } while (0)
#define PV_LOAD_B(dst, nh) do { _Pragma("unroll")                             \
    for (int nf = 0; nf < 2; ++nf)                                            \
      dst[nf] = *(const half8*)(buf + bRd[nh] + nf * 1024); } while (0)
#define PV_MFMA(mh, nh, br) do { _Pragma("unroll")                            \
    for (int mf = 0; mf < 2; ++mf) { _Pragma("unroll")                        \
      for (int nf = 0; nf < 2; ++nf) {                                        \
        f32x4& ac = acc[(mh) * 2 + mf][(nh) * 2 + nf];                        \
        ac = __builtin_amdgcn_mfma_f32_16x16x32_f16(ar[mf], br[nf], ac, 0, 0, 0); \
      } } } while (0)

  // prologue: tiles 0 (buf0) and 1 (buf1)
  PV_AISSUE(0);
  PV_STAGE_B(0, 0, 0); PV_STAGE_B(1, 0, 0);
  uint4 rawA1 = *(const uint4*)(aSrc + 32);
  float4 uva1 = *(const float4*)(U + 32 + ucol);
  float4 uvb1 = *(const float4*)(U + 32 + ucol + 4);
  PV_STAGE_B(0, 1, 1); PV_STAGE_B(1, 1, 1);
  VMW2();  // A/u data ready
  PV_AWRITE(0);
  rawA = rawA1; uva = uva1; uvb = uvb1;
  PV_AWRITE(1);
  asm volatile("s_waitcnt lgkmcnt(0)" ::: "memory");
  BAR();
  VMW0();  // buf0+buf1 B complete before first reads

  f32x4 acc[4][4] = {};
  half8 ar[2], b0r[2], b1r[2];
  const int NT = T_ / 32;  // 64 K-tiles

  for (int it = 0; it < NT / 2; ++it) {
    #pragma unroll
    for (int h = 0; h < 2; ++h) {
      const char* buf = lds + h * BUFB;
      const int tt = 2 * it + 2 + h;
      const bool st = (tt < NT);
      // phase 1
      PV_LOAD_A(0); PV_LOAD_B(b0r, 0);
      if (st) PV_AISSUE(tt);
      BAR(); LGKM0();
      __builtin_amdgcn_s_setprio(1); PV_MFMA(0, 0, b0r);
      __builtin_amdgcn_s_setprio(0); BAR();
      // phase 2
      PV_LOAD_B(b1r, 1);
      if (st) PV_STAGE_B(0, h, tt);
      BAR(); LGKM0();
      __builtin_amdgcn_s_setprio(1); PV_MFMA(0, 1, b1r);
      __builtin_amdgcn_s_setprio(0); BAR();
      // phase 3
      PV_LOAD_A(1);
      if (st) PV_STAGE_B(1, h, tt);
      BAR(); LGKM0();
      __builtin_amdgcn_s_setprio(1); PV_MFMA(1, 1, b1r);
      __builtin_amdgcn_s_setprio(0); BAR();
      // phase 4: drain A/u + prior B, write exp*u tile, drain ds_write
      if (st) {
        VMW2(); PV_AWRITE(h);
        asm volatile("s_waitcnt lgkmcnt(0)" ::: "memory");
      }
      BAR();
      __builtin_amdgcn_s_setprio(1); PV_MFMA(1, 0, b0r);
      __builtin_amdgcn_s_setprio(0);
      if (!st) VMW0();
      BAR();
    }
  }

  #pragma unroll
  for (int m = 0; m < 4; ++m) {
    int rowoff = (m >> 1) * 32 + (m & 1) * 16;
    #pragma unroll
    for (int n = 0; n < 4; ++n) {
      int coloff = (n >> 1) * 32 + (n & 1) * 16;
      #pragma unroll
      for (int r = 0; r < 4; ++r) {
        int row = brow + wr * 64 + rowoff + g4 * 4 + r;
        int col = bcol + wc * 64 + coloff + l15;
        Co[(size_t)row * D_ + col] = acc[m][n][r];
      }
    }
  }
#undef PV_STAGE_B
#undef PV_AISSUE
#undef PV_AWRITE
#undef PV_LOAD_A
#undef PV_LOAD_B
#undef PV_MFMA
}

// ------- invert column sums ----------------------------------------
__global__ __launch_bounds__(256) void sm_stats(const float* __restrict__ cs,
                                                float* __restrict__ stats) {
  int i = blockIdx.x * 256 + threadIdx.x;  // b*2048 + k
  stats[i] = 1.0f / cs[i];
}

// --------------------------------------------------------------------
extern "C" void kernel_launch(void* const* d_in, const int* in_sizes, int n_in,
                              void* d_out, int out_size, void* d_ws, size_t ws_size,
                              hipStream_t stream) {
  const float* x  = (const float*)d_in[0];
  const float* Wq = (const float*)d_in[1];
  const float* Wk = (const float*)d_in[2];
  const float* Wv = (const float*)d_in[3];
  float* out = (float*)d_out;

  char* ws = (char*)d_ws;
  const size_t MB = 1024ull * 1024ull;
  unsigned short* scoresh = (unsigned short*)(ws);             // 32 MB fp16
  unsigned short* QKVh = (unsigned short*)(ws + 32 * MB);      // 48 MB [8192][3072]
  unsigned short* Vt   = (unsigned short*)(ws + 80 * MB);      // 16 MB [4][1024][2048]
  unsigned short* xh   = (unsigned short*)(ws + 96 * MB);      // 16 MB fp16 x
  unsigned short* Wt   = (unsigned short*)(ws + 112 * MB);     // 6 MB  [3072][1024]
  float* colsum = (float*)(ws + 118 * MB);                     // 32 KB [4][2048]
  float* stats  = (float*)(ws + 118 * MB + 64 * 1024);         // 32 KB fp32 u

  // 1. x -> fp16 (+ zero colsum for the fused-colsum scores pass)
  tofp16_kernel<<<MTOK * D_ / 4 / 256, 256, 0, stream>>>(
      (const float4*)x, (ushort4*)xh, MTOK * D_ / 4,
      (float4*)colsum, B_ * T_ / 4);

  // 2. transpose + concat W -> fp16
  wcat_t_kernel<<<dim3(32, 32, 3), 256, 0, stream>>>(Wq, Wk, Wv, Wt);

  // 3. fused QKV projection (FM=4, 768 blocks -> 3 blocks/CU)
  gemm8p<1><<<dim3(3072 / 256, MTOK / 128, 1), 512, 0, stream>>>(
      xh, Wt, QKVh, nullptr, D_, D_, D_, 3072, 0, 0, 0);

  // 4. V transpose -> Vt[b][d][t]
  vtrans_kernel<<<dim3(T_ / 64, D_ / 64, B_), 256, 0, stream>>>(QKVh, Vt);

  // 5. scores = Q K^T, fp16 out + fused column-sum of exp(s-64)
  gemm8p<2><<<dim3(T_ / 256, T_ / 128, B_), 512, 0, stream>>>(
      QKVh, QKVh + 1024, scoresh, colsum, D_, 3072, 3072, T_,
      (long)T_ * 3072, (long)T_ * 3072, (long)T_ * T_);

  // 6. u = 1/colsum
  sm_stats<<<B_ * T_ / 256, 256, 0, stream>>>(colsum, stats);

  // 7. out = exp(S-64)*u @ V (grid 256, plain stores)
  gemmPV<<<dim3(D_ / 256, T_ / 128, B_), 512, 0, stream>>>(
      scoresh, stats, Vt, out);
}